// Round 3
// baseline (502.762 us; speedup 1.0000x reference)
//
#include <hip/hip_runtime.h>
#include <hip/hip_bf16.h>

typedef __bf16 bf16x8 __attribute__((ext_vector_type(8)));
typedef float f32x4 __attribute__((ext_vector_type(4)));
typedef _Float16 h8 __attribute__((ext_vector_type(8)));
typedef unsigned short u16x8 __attribute__((ext_vector_type(8)));

__device__ inline unsigned short f2b(float x) {
    __hip_bfloat16 h = __float2bfloat16(x);
    return __builtin_bit_cast(unsigned short, h);
}

__device__ inline void gload16(const void* g, void* l) {
    __builtin_amdgcn_global_load_lds(
        (const __attribute__((address_space(1))) unsigned int*)g,
        (__attribute__((address_space(3))) unsigned int*)l, 16, 0, 0);
}

// 16 MFMA quadrant, compile-time acc indices (rule #20).
#define MFMA_BLK(AF, BF, MO, NO)                                               \
    __builtin_amdgcn_s_setprio(1);                                             \
    _Pragma("unroll")                                                          \
    for (int m_ = 0; m_ < 4; ++m_) {                                           \
        _Pragma("unroll")                                                      \
        for (int n_ = 0; n_ < 2; ++n_) {                                       \
            acc[(MO) + m_][(NO) + n_] =                                        \
                __builtin_amdgcn_mfma_f32_16x16x32_bf16(                       \
                    AF[m_][0], BF[n_][0], acc[(MO) + m_][(NO) + n_], 0, 0, 0); \
            acc[(MO) + m_][(NO) + n_] =                                        \
                __builtin_amdgcn_mfma_f32_16x16x32_bf16(                       \
                    AF[m_][1], BF[n_][1], acc[(MO) + m_][(NO) + n_], 0, 0, 0); \
        }                                                                      \
    }                                                                          \
    __builtin_amdgcn_s_setprio(0);

// ---------------------------------------------------------------------------
// NT GEMM: C[M,N] = A[M,K] * B[N,K]^T (+bias), A/B bf16 K-contiguous.
// 256x256 tile, BK=64, 512 threads = 8 waves (2M x 4N), wave tile 128x64,
// mfma 16x16x32. LDS = 2 buffers x [A(256x64) | B(256x64)] = 128 KiB.
// Pipelined quadrant schedule (LDS pipe overlaps MFMA pipe within-wave):
// each phase's MFMA uses fragments read one phase EARLIER; the ds_reads it
// issues drain under the MFMA. Phases = (m-half, n-half) quadrants:
//   P0: issue B1(kt);    MFMA A0*B0  -> acc[0..3][0..1]
//   P1: issue A1(kt);    MFMA A0*B1  -> acc[0..3][2..3]
//   P2: lgkm(0); barrier W; stage(kt+2); vmcnt(8); barrier R;
//       issue A0(kt+1);  MFMA A1*B0  -> acc[4..7][0..1]
//   P3: issue B0(kt+1);  MFMA A1*B1  -> acc[4..7][2..3]
// 2 barriers/tile (vs 8): W = WAR fence (all waves' reads of buf(kt) drained
// via the single per-tile lgkmcnt(0)) before stage(kt+2) overwrites it;
// R = buf(kt+1) readiness (vmcnt(8) = all but the 8 just-issued kt+2 loads
// landed => stage(kt+1), issued a full tile ago, complete). vmcnt never
// drains to 0 mid-loop. Swizzle unchanged from round 2 (conflict count 0):
// 16B granule g' = g ^ (row&7), pre-swizzled global source + swizzled read.
// EPI: 0 = QKV router (bias, q/k normal, v transposed), 1 = f16*scale (scores),
//      2 = bf16 (PV->ao), 3 = f32+bias (final out)
// ---------------------------------------------------------------------------
template<int EPI, int SWZ>
__global__ __launch_bounds__(512, 2) void gemm_nt(
    const unsigned short* __restrict__ A, const unsigned short* __restrict__ B,
    long aZ, long bZ, int lda, int ldb, int K,
    const float* __restrict__ bias,
    void* __restrict__ C0, void* __restrict__ C1, void* __restrict__ C2,
    long cZ, int ldc, float scale, int gx, int gy)
{
    __shared__ __attribute__((aligned(16))) unsigned short lds[2][4][8192];

    int wgid;
    if (SWZ) {
        const int nwg = (int)gridDim.x;
        const int bid = (int)blockIdx.x;
        const int qch = nwg >> 3, rch = nwg & 7;
        const int xcd = bid & 7, idx = bid >> 3;
        wgid = (xcd < rch ? xcd * (qch + 1)
                          : rch * (qch + 1) + (xcd - rch) * qch) + idx;
    } else {
        wgid = (int)blockIdx.x;
    }
    const int bx = wgid % gx;
    const int rem = wgid / gx;
    const int by = rem % gy;
    const int z = rem / gy;

    const int t = threadIdx.x;
    const int lane = t & 63, wid = t >> 6;
    const int wr = wid >> 2, wc = wid & 3;           // 2 x 4 wave grid
    const int wc1 = wc & 1, wch = wc >> 1;
    const int tileM = by * 256, tileN = bx * 256;
    A += (size_t)z * aZ;
    B += (size_t)z * bZ;

    f32x4 acc[8][4] = {};

    // ---- read geometry: frag element k = ks*32 + qw*8 (qw = lane>>4);
    // granule g = ks*4+qw; physical granule g^(row&7), row&7 == lane&7.
    const int l4 = lane & 15, qw = lane >> 4, sw = lane & 7;
    const int aoff0 = l4 * 64 + ((qw ^ sw) << 3);
    const int aoff1 = l4 * 64 + (((4 | qw) ^ sw) << 3);

    // ---- staging geometry: 256 rows x 64 K per matrix per tile, 8 loads/thr.
    // chunk c = j*512 + t: LDS row = j*64 + (t>>3), phys granule = t&7,
    // source granule = (t&7) ^ (row&7) = (t ^ (t>>3)) & 7  (j*64 = 0 mod 8).
    const int srow = t >> 3;
    const int sg = ((t ^ (t >> 3)) & 7) << 3;
    const unsigned short* Asrc = A + (size_t)(tileM + srow) * lda + sg;
    const unsigned short* Bsrc = B + (size_t)(tileN + srow) * ldb + sg;

    auto stageT = [&](int kt) {
        const int b = kt & 1;
        char* dA = (char*)&lds[b][0][0] + wid * 1024;
        char* dB = (char*)&lds[b][2][0] + wid * 1024;
        const unsigned short* sA = Asrc + kt * 64;
        const unsigned short* sB = Bsrc + kt * 64;
        gload16(sA, dA);
        gload16(sA + (size_t)64 * lda, dA + 8192);
        gload16(sA + (size_t)128 * lda, dA + 16384);
        gload16(sA + (size_t)192 * lda, dA + 24576);
        gload16(sB, dB);
        gload16(sB + (size_t)64 * ldb, dB + 8192);
        gload16(sB + (size_t)128 * ldb, dB + 16384);
        gload16(sB + (size_t)192 * ldb, dB + 24576);
    };

    const int NT = K >> 6;                            // BK = 64, K % 64 == 0
    bf16x8 af0[4][2], af1[4][2], bf0[2][2], bf1[2][2];

    stageT(0);
    if (NT > 1) {
        stageT(1);
        asm volatile("s_waitcnt vmcnt(8)" ::: "memory");   // tile 0 landed
    } else {
        asm volatile("s_waitcnt vmcnt(0)" ::: "memory");
    }
    asm volatile("s_barrier" ::: "memory");
    {   // pre-read A0(0), B0(0)
        const unsigned short* Ah = &lds[0][wr][0];
        const unsigned short* Bh = &lds[0][2 + wch][0] + wc1 * 4096;
#pragma unroll
        for (int m = 0; m < 4; ++m) {
            af0[m][0] = *(const bf16x8*)(Ah + m * 1024 + aoff0);
            af0[m][1] = *(const bf16x8*)(Ah + m * 1024 + aoff1);
        }
#pragma unroll
        for (int n = 0; n < 2; ++n) {
            bf0[n][0] = *(const bf16x8*)(Bh + n * 1024 + aoff0);
            bf0[n][1] = *(const bf16x8*)(Bh + n * 1024 + aoff1);
        }
    }

    for (int kt = 0; kt < NT; ++kt) {
        const unsigned short* Ah = &lds[kt & 1][wr][0];
        const unsigned short* Bh = &lds[kt & 1][2 + wch][0] + wc1 * 4096;
        const unsigned short* An = &lds[(kt + 1) & 1][wr][0];
        const unsigned short* Bn = &lds[(kt + 1) & 1][2 + wch][0] + wc1 * 4096;

        // ---- P0: issue B1(kt); MFMA A0*B0
#pragma unroll
        for (int n = 0; n < 2; ++n) {
            bf1[n][0] = *(const bf16x8*)(Bh + (2 + n) * 1024 + aoff0);
            bf1[n][1] = *(const bf16x8*)(Bh + (2 + n) * 1024 + aoff1);
        }
        MFMA_BLK(af0, bf0, 0, 0)

        // ---- P1: issue A1(kt); MFMA A0*B1
#pragma unroll
        for (int m = 0; m < 4; ++m) {
            af1[m][0] = *(const bf16x8*)(Ah + (4 + m) * 1024 + aoff0);
            af1[m][1] = *(const bf16x8*)(Ah + (4 + m) * 1024 + aoff1);
        }
        MFMA_BLK(af0, bf1, 0, 2)

        // ---- P2: drain + W + stage(kt+2) + vmcnt + R + issue A0(kt+1);
        //          MFMA A1*B0
        asm volatile("s_waitcnt lgkmcnt(0)" ::: "memory");
        asm volatile("s_barrier" ::: "memory");              // W
        if (kt + 2 < NT) stageT(kt + 2);
        if (kt + 1 < NT) {
            if (kt + 2 < NT) asm volatile("s_waitcnt vmcnt(8)" ::: "memory");
            else             asm volatile("s_waitcnt vmcnt(0)" ::: "memory");
            asm volatile("s_barrier" ::: "memory");          // R
#pragma unroll
            for (int m = 0; m < 4; ++m) {
                af0[m][0] = *(const bf16x8*)(An + m * 1024 + aoff0);
                af0[m][1] = *(const bf16x8*)(An + m * 1024 + aoff1);
            }
        }
        MFMA_BLK(af1, bf0, 4, 0)

        // ---- P3: issue B0(kt+1); MFMA A1*B1
        if (kt + 1 < NT) {
#pragma unroll
            for (int n = 0; n < 2; ++n) {
                bf0[n][0] = *(const bf16x8*)(Bn + n * 1024 + aoff0);
                bf0[n][1] = *(const bf16x8*)(Bn + n * 1024 + aoff1);
            }
        }
        MFMA_BLK(af1, bf1, 4, 2)
    }

    // epilogue: C/D layout col = lane&15, row = (lane>>4)*4 + j  [m89-verified]
    const int lr = lane >> 4, lc = lane & 15;
#pragma unroll
    for (int m = 0; m < 8; ++m) {
#pragma unroll
        for (int n = 0; n < 4; ++n) {
            f32x4 v = acc[m][n];
            const int col = tileN + wc * 64 + n * 16 + lc;
            const int row0 = tileM + wr * 128 + m * 16 + lr * 4;
            if (EPI == 0) {
                const float bv = bias[col];
                if (col < 2048) {
                    unsigned short* dst = (col < 1024) ? (unsigned short*)C0
                                                       : (unsigned short*)C1;
                    const int cc = col & 1023;
#pragma unroll
                    for (int j = 0; j < 4; ++j)
                        dst[(size_t)(row0 + j) * 1024 + cc] = f2b(v[j] + bv);
                } else {
                    // vT[b][col-2048][s], rows row0..row0+3 are consecutive s
                    const int b = row0 >> 12, s = row0 & 4095;
                    ushort4 h4;
                    h4.x = f2b(v[0] + bv); h4.y = f2b(v[1] + bv);
                    h4.z = f2b(v[2] + bv); h4.w = f2b(v[3] + bv);
                    *(ushort4*)((unsigned short*)C2 +
                                ((size_t)b * 1024 + (col - 2048)) * 4096 + s) = h4;
                }
            } else if (EPI == 1) {
#pragma unroll
                for (int j = 0; j < 4; ++j)
                    ((_Float16*)C0)[(size_t)z * cZ + (size_t)(row0 + j) * ldc + col] =
                        (_Float16)(v[j] * scale);
            } else if (EPI == 2) {
#pragma unroll
                for (int j = 0; j < 4; ++j)
                    ((unsigned short*)C0)[(size_t)z * cZ + (size_t)(row0 + j) * ldc + col] =
                        f2b(v[j]);
            } else {
#pragma unroll
                for (int j = 0; j < 4; ++j)
                    ((float*)C0)[(size_t)(row0 + j) * ldc + col] = v[j] + bias[col];
            }
        }
    }
}

// ---------------------------------------------------------------------------
// Row softmax in-place: reads 4096 f16, writes 4096 bf16 over the same bytes.
// ---------------------------------------------------------------------------
__global__ __launch_bounds__(256) void softmax_rows(unsigned short* __restrict__ sc)
{
    const size_t rowoff = (size_t)blockIdx.x * 4096;
    const int t = threadIdx.x;

    h8 a = *(const h8*)(sc + rowoff + t * 8);
    h8 b = *(const h8*)(sc + rowoff + 2048 + t * 8);
    float v[16];
#pragma unroll
    for (int i = 0; i < 8; ++i) { v[i] = (float)a[i]; v[8 + i] = (float)b[i]; }

    float mx = -1e30f;
#pragma unroll
    for (int i = 0; i < 16; ++i) mx = fmaxf(mx, v[i]);
#pragma unroll
    for (int o = 32; o > 0; o >>= 1) mx = fmaxf(mx, __shfl_xor(mx, o));
    __shared__ float redm[4];
    if ((t & 63) == 0) redm[t >> 6] = mx;
    __syncthreads();
    mx = fmaxf(fmaxf(redm[0], redm[1]), fmaxf(redm[2], redm[3]));

    float sum = 0.f;
#pragma unroll
    for (int i = 0; i < 16; ++i) { v[i] = expf(v[i] - mx); sum += v[i]; }
#pragma unroll
    for (int o = 32; o > 0; o >>= 1) sum += __shfl_xor(sum, o);
    __shared__ float reds[4];
    if ((t & 63) == 0) reds[t >> 6] = sum;
    __syncthreads();
    sum = reds[0] + reds[1] + reds[2] + reds[3];
    const float rs = 1.f / sum;

    u16x8 w0, w1;
#pragma unroll
    for (int i = 0; i < 8; ++i) {
        w0[i] = f2b(v[i] * rs);
        w1[i] = f2b(v[8 + i] * rs);
    }
    *(u16x8*)(sc + rowoff + t * 8) = w0;
    *(u16x8*)(sc + rowoff + 2048 + t * 8) = w1;
}

__global__ __launch_bounds__(256) void cast_bf16(
    const float* __restrict__ in, unsigned short* __restrict__ out, int n4)
{
    const int i = blockIdx.x * 256 + threadIdx.x;
    if (i < n4) {
        float4 f = ((const float4*)in)[i];
        ushort4 o;
        o.x = f2b(f.x); o.y = f2b(f.y); o.z = f2b(f.z); o.w = f2b(f.w);
        ((ushort4*)out)[i] = o;
    }
}

// ---------------------------------------------------------------------------
extern "C" void kernel_launch(void* const* d_in, const int* in_sizes, int n_in,
                              void* d_out, int out_size, void* d_ws, size_t ws_size,
                              hipStream_t stream)
{
    const float* x      = (const float*)d_in[0];   // [4,4096,1024]
    const float* qkv_w  = (const float*)d_in[1];   // [3072,1024]
    const float* qkv_b  = (const float*)d_in[2];   // [3072]
    const float* out_w  = (const float*)d_in[3];   // [1024,1024]
    const float* out_b  = (const float*)d_in[4];   // [1024]
    float* out = (float*)d_out;                    // [4,4096,1024] fp32

    unsigned short* W = (unsigned short*)d_ws;
    const size_t M16 = 16777216;   // one [4,4096,1024] bf16 tensor (ushorts)

    if (ws_size >= 236978176ull) {
        // ---- big mode: 226 MiB peak ----
        unsigned short* sc   = W;
        unsigned short* q    = sc + 67108864;
        unsigned short* kk   = q + M16;
        unsigned short* vT   = kk + M16;
        unsigned short* wo   = vT + M16;
        unsigned short* xb   = sc;            // transient, dead before sc write
        unsigned short* wqkv = sc + M16;      // transient
        unsigned short* ao   = q;             // q dead after scores GEMM

        cast_bf16<<<16384, 256, 0, stream>>>(x, xb, 4194304);
        cast_bf16<<<3072, 256, 0, stream>>>(qkv_w, wqkv, 786432);
        cast_bf16<<<1024, 256, 0, stream>>>(out_w, wo, 262144);

        gemm_nt<0, 0><<<12 * 64, 512, 0, stream>>>(
            xb, wqkv, 0, 0, 1024, 1024, 1024, qkv_b, q, kk, vT, 0, 0, 0.f, 12, 64);

        gemm_nt<1, 0><<<16 * 16 * 4, 512, 0, stream>>>(
            q, kk, 4194304, 4194304, 1024, 1024, 1024, nullptr,
            sc, nullptr, nullptr, 16777216, 4096, 0.03125f, 16, 16);

        softmax_rows<<<16384, 256, 0, stream>>>(sc);

        gemm_nt<2, 1><<<4 * 16 * 4, 512, 0, stream>>>(
            sc, vT, 16777216, 4194304, 4096, 4096, 4096, nullptr,
            ao, nullptr, nullptr, 4194304, 1024, 0.f, 4, 16);

        gemm_nt<3, 0><<<4 * 64, 512, 0, stream>>>(
            ao, wo, 0, 0, 1024, 1024, 1024, out_b,
            out, nullptr, nullptr, 0, 1024, 0.f, 4, 64);
    } else {
        // ---- small mode: 168 MiB peak, per-batch scores buffer ----
        unsigned short* sc   = W;
        unsigned short* q    = sc + M16;
        unsigned short* kk   = q + M16;
        unsigned short* vT   = kk + M16;
        unsigned short* ao   = vT + M16;
        unsigned short* wo   = ao + M16;
        unsigned short* wqkv = wo + 1048576;
        unsigned short* xb   = sc;

        cast_bf16<<<16384, 256, 0, stream>>>(x, xb, 4194304);
        cast_bf16<<<3072, 256, 0, stream>>>(qkv_w, wqkv, 786432);
        cast_bf16<<<1024, 256, 0, stream>>>(out_w, wo, 262144);

        gemm_nt<0, 0><<<12 * 64, 512, 0, stream>>>(
            xb, wqkv, 0, 0, 1024, 1024, 1024, qkv_b, q, kk, vT, 0, 0, 0.f, 12, 64);

        for (int z = 0; z < 4; ++z) {
            const size_t zo = (size_t)z * 4194304;
            gemm_nt<1, 0><<<16 * 16, 512, 0, stream>>>(
                q + zo, kk + zo, 0, 0, 1024, 1024, 1024, nullptr,
                sc, nullptr, nullptr, 0, 4096, 0.03125f, 16, 16);
            softmax_rows<<<4096, 256, 0, stream>>>(sc);
            gemm_nt<2, 1><<<4 * 16, 512, 0, stream>>>(
                sc, vT + zo, 0, 0, 4096, 4096, 4096, nullptr,
                ao + zo, nullptr, nullptr, 0, 1024, 0.f, 4, 16);
        }

        gemm_nt<3, 0><<<4 * 64, 512, 0, stream>>>(
            ao, wo, 0, 0, 1024, 1024, 1024, out_b,
            out, nullptr, nullptr, 0, 1024, 0.f, 4, 64);
    }
}

// Round 4
// 496.516 us; speedup vs baseline: 1.0126x; 1.0126x over previous
//
#include <hip/hip_runtime.h>
#include <hip/hip_bf16.h>

typedef __bf16 bf16x8 __attribute__((ext_vector_type(8)));
typedef float f32x4 __attribute__((ext_vector_type(4)));
typedef float f32x16 __attribute__((ext_vector_type(16)));
typedef _Float16 h8 __attribute__((ext_vector_type(8)));
typedef unsigned short u16x8 __attribute__((ext_vector_type(8)));

__device__ inline unsigned short f2b(float x) {
    __hip_bfloat16 h = __float2bfloat16(x);
    return __builtin_bit_cast(unsigned short, h);
}

__device__ inline void gload16(const void* g, void* l) {
    __builtin_amdgcn_global_load_lds(
        (const __attribute__((address_space(1))) unsigned int*)g,
        (__attribute__((address_space(3))) unsigned int*)l, 16, 0, 0);
}

// ---------------------------------------------------------------------------
// NT GEMM: C[M,N] = A[M,K] * B[N,K]^T (+bias), A/B bf16 K-contiguous.
// 256x256 tile, BK=64, 512 threads = 8 waves (2M x 4N), wave tile 128x64,
// mfma_f32_32x32x16_bf16 (2495 TF ceiling vs 2075 for 16x16 — m119/m06).
// LDS = 2 buffers x [A(256x64) | B(256x64)] = 128 KiB.
// 4 phases per K-tile, ONE barrier per phase (trailing only):
//   P(p): [P0: read 8 B frags] read 4 A frags (m-pos p); stage per schedule;
//         [P3: counted vmcnt]; lgkmcnt(0); setprio(1); 8 MFMA; setprio(0);
//         s_barrier
// Leading barrier is redundant: each wave's lgkmcnt(0) precedes its trailing
// barrier, so any wave at P2's stageB overwrite has 2 barriers behind which
// all waves' B-reads (P0) were drained. Staging: A(t+1)@P0/P1 (opposite
// buffer), B(t+2)@P2/P3 (current buffer, WAR-safe per above); vmcnt(4)@P3
// forces tile t+1 landed, leaves the 2 newest B half-tiles in flight —
// never drains to 0 mid-loop (T4).
// Swizzle (0-conflict, verified r2): 16B granule g' = g ^ (row&7); source
// pre-swizzled within the row's 128B line, gload_lds dest linear, ds_read
// applies the same involution. For 32x32 frags each granule value is hit by
// exactly 8 lanes -> 32 B/bank, perfectly even.
// A/B frag layout: row = lane&31, k = (lane>>5)*8 + 0..7 (contiguous-8, the
// verified 16x16x32 analog). C/D: col=lane&31, row=(r&3)+8(r>>2)+4(lane>>5).
// EPI: 0 = QKV router (bias, q/k normal, v transposed), 1 = f16*scale (scores),
//      2 = bf16 (PV->ao), 3 = f32+bias (final out)
// ---------------------------------------------------------------------------
template<int EPI, int SWZ>
__global__ __launch_bounds__(512, 2) void gemm_nt(
    const unsigned short* __restrict__ A, const unsigned short* __restrict__ B,
    long aZ, long bZ, int lda, int ldb, int K,
    const float* __restrict__ bias,
    void* __restrict__ C0, void* __restrict__ C1, void* __restrict__ C2,
    long cZ, int ldc, float scale, int gx, int gy)
{
    __shared__ __attribute__((aligned(16))) unsigned short lds[2][4][8192];

    int wgid;
    if (SWZ) {
        const int nwg = (int)gridDim.x;
        const int bid = (int)blockIdx.x;
        const int qch = nwg >> 3, rch = nwg & 7;
        const int xcd = bid & 7, idx = bid >> 3;
        wgid = (xcd < rch ? xcd * (qch + 1)
                          : rch * (qch + 1) + (xcd - rch) * qch) + idx;
    } else {
        wgid = (int)blockIdx.x;
    }
    const int bx = wgid % gx;
    const int rem = wgid / gx;
    const int by = rem % gy;
    const int z = rem / gy;

    const int t = threadIdx.x;
    const int lane = t & 63, wid = t >> 6;
    const int wr = wid >> 2, wc = wid & 3;           // 2 x 4 wave grid
    const int tileM = by * 256, tileN = bx * 256;
    A += (size_t)z * aZ;
    B += (size_t)z * bZ;

    f32x16 acc[4][2] = {};

    // ---- read geometry (32x32x16): row = lane&31, k = (lane>>5)*8 + ks*16.
    // logical granule g = ks*2 + (lane>>5); physical g^(row&7), row&7=lane&7.
    const int l5 = lane & 31, hi = lane >> 5, sw = lane & 7;
    const int rb = l5 * 64;                           // row base (ushorts)
    const int kg0 = (((0 + hi) ^ sw) << 3);
    const int kg1 = (((2 + hi) ^ sw) << 3);
    const int kg2 = (((4 + hi) ^ sw) << 3);
    const int kg3 = (((6 + hi) ^ sw) << 3);

    // ---- staging geometry: half-tile = 128 rows x 64 K, 2 gload16/thread.
    // chunk: row = t>>3 (+64 for 2nd), phys granule = t&7,
    // source granule = (t&7) ^ (row&7) = (t ^ (t>>3)) & 7.
    const int srow = t >> 3;
    const int sg = ((t ^ (t >> 3)) & 7) << 3;
    const unsigned short* Asrc = A + (size_t)(tileM + srow) * lda + sg;
    const unsigned short* Bsrc = B + (size_t)(tileN + srow) * ldb + sg;

    auto stageA = [&](int kt, int h) {
        char* dst = (char*)&lds[kt & 1][h][0] + wid * 1024;
        const unsigned short* s = Asrc + (size_t)(h * 128) * lda + kt * 64;
        gload16(s, dst);
        gload16(s + (size_t)64 * lda, dst + 8192);
    };
    auto stageB = [&](int kt, int h) {
        char* dst = (char*)&lds[kt & 1][2 + h][0] + wid * 1024;
        const unsigned short* s = Bsrc + (size_t)(h * 128) * ldb + kt * 64;
        gload16(s, dst);
        gload16(s + (size_t)64 * ldb, dst + 8192);
    };

    const int NT = K >> 6;                            // BK = 64, K % 64 == 0
    stageA(0, 0); stageA(0, 1); stageB(0, 0); stageB(0, 1);
    if (NT > 1) {
        stageB(1, 0); stageB(1, 1);
        asm volatile("s_waitcnt vmcnt(4)" ::: "memory");   // tile 0 landed
    } else {
        asm volatile("s_waitcnt vmcnt(0)" ::: "memory");
    }
    asm volatile("s_barrier" ::: "memory");

    for (int kt = 0; kt < NT; ++kt) {
        const unsigned short* Ah = &lds[kt & 1][0][0] + wr * 8192;
        const unsigned short* Bh = &lds[kt & 1][2][0] + wc * 4096;
        bf16x8 bfr[2][4];
#pragma unroll
        for (int p = 0; p < 4; ++p) {
            if (p == 0) {
#pragma unroll
                for (int n = 0; n < 2; ++n) {
                    bfr[n][0] = *(const bf16x8*)(Bh + n * 2048 + rb + kg0);
                    bfr[n][1] = *(const bf16x8*)(Bh + n * 2048 + rb + kg1);
                    bfr[n][2] = *(const bf16x8*)(Bh + n * 2048 + rb + kg2);
                    bfr[n][3] = *(const bf16x8*)(Bh + n * 2048 + rb + kg3);
                }
            }
            bf16x8 a0 = *(const bf16x8*)(Ah + p * 2048 + rb + kg0);
            bf16x8 a1 = *(const bf16x8*)(Ah + p * 2048 + rb + kg1);
            bf16x8 a2 = *(const bf16x8*)(Ah + p * 2048 + rb + kg2);
            bf16x8 a3 = *(const bf16x8*)(Ah + p * 2048 + rb + kg3);
            if (p == 0 && kt + 1 < NT) stageA(kt + 1, 0);
            if (p == 1 && kt + 1 < NT) stageA(kt + 1, 1);
            if (p == 2 && kt + 2 < NT) stageB(kt + 2, 0);
            if (p == 3 && kt + 2 < NT) stageB(kt + 2, 1);
            if (p == 3 && kt + 1 < NT) {
                if (kt + 2 < NT) asm volatile("s_waitcnt vmcnt(4)" ::: "memory");
                else             asm volatile("s_waitcnt vmcnt(0)" ::: "memory");
            }
            asm volatile("s_waitcnt lgkmcnt(0)" ::: "memory");
            __builtin_amdgcn_s_setprio(1);
            acc[p][0] = __builtin_amdgcn_mfma_f32_32x32x16_bf16(a0, bfr[0][0], acc[p][0], 0, 0, 0);
            acc[p][1] = __builtin_amdgcn_mfma_f32_32x32x16_bf16(a0, bfr[1][0], acc[p][1], 0, 0, 0);
            acc[p][0] = __builtin_amdgcn_mfma_f32_32x32x16_bf16(a1, bfr[0][1], acc[p][0], 0, 0, 0);
            acc[p][1] = __builtin_amdgcn_mfma_f32_32x32x16_bf16(a1, bfr[1][1], acc[p][1], 0, 0, 0);
            acc[p][0] = __builtin_amdgcn_mfma_f32_32x32x16_bf16(a2, bfr[0][2], acc[p][0], 0, 0, 0);
            acc[p][1] = __builtin_amdgcn_mfma_f32_32x32x16_bf16(a2, bfr[1][2], acc[p][1], 0, 0, 0);
            acc[p][0] = __builtin_amdgcn_mfma_f32_32x32x16_bf16(a3, bfr[0][3], acc[p][0], 0, 0, 0);
            acc[p][1] = __builtin_amdgcn_mfma_f32_32x32x16_bf16(a3, bfr[1][3], acc[p][1], 0, 0, 0);
            __builtin_amdgcn_s_setprio(0);
            asm volatile("s_barrier" ::: "memory");
        }
    }

    // epilogue: C/D 32x32 layout: col = lane&31, row = (r&3)+8*(r>>2)+4*hi.
    const int lr4 = hi * 4;
#pragma unroll
    for (int m = 0; m < 4; ++m) {
#pragma unroll
        for (int n = 0; n < 2; ++n) {
            const int col = tileN + wc * 64 + n * 32 + l5;
            float bv = 0.f;
            if (EPI == 0 || EPI == 3) bv = bias[col];
#pragma unroll
            for (int g = 0; g < 4; ++g) {
                const int row0 = tileM + wr * 128 + m * 32 + g * 8 + lr4;
                float v0 = acc[m][n][g * 4 + 0], v1 = acc[m][n][g * 4 + 1];
                float v2 = acc[m][n][g * 4 + 2], v3 = acc[m][n][g * 4 + 3];
                if (EPI == 0) {
                    if (col < 2048) {
                        unsigned short* dst = (col < 1024) ? (unsigned short*)C0
                                                           : (unsigned short*)C1;
                        const int cc = col & 1023;
                        dst[(size_t)(row0 + 0) * 1024 + cc] = f2b(v0 + bv);
                        dst[(size_t)(row0 + 1) * 1024 + cc] = f2b(v1 + bv);
                        dst[(size_t)(row0 + 2) * 1024 + cc] = f2b(v2 + bv);
                        dst[(size_t)(row0 + 3) * 1024 + cc] = f2b(v3 + bv);
                    } else {
                        // vT[b][col-2048][s], rows row0.. are consecutive s
                        const int b = row0 >> 12, s = row0 & 4095;
                        ushort4 h4;
                        h4.x = f2b(v0 + bv); h4.y = f2b(v1 + bv);
                        h4.z = f2b(v2 + bv); h4.w = f2b(v3 + bv);
                        *(ushort4*)((unsigned short*)C2 +
                                    ((size_t)b * 1024 + (col - 2048)) * 4096 + s) = h4;
                    }
                } else if (EPI == 1) {
                    _Float16* dst = (_Float16*)C0 + (size_t)z * cZ;
                    dst[(size_t)(row0 + 0) * ldc + col] = (_Float16)(v0 * scale);
                    dst[(size_t)(row0 + 1) * ldc + col] = (_Float16)(v1 * scale);
                    dst[(size_t)(row0 + 2) * ldc + col] = (_Float16)(v2 * scale);
                    dst[(size_t)(row0 + 3) * ldc + col] = (_Float16)(v3 * scale);
                } else if (EPI == 2) {
                    unsigned short* dst = (unsigned short*)C0 + (size_t)z * cZ;
                    dst[(size_t)(row0 + 0) * ldc + col] = f2b(v0);
                    dst[(size_t)(row0 + 1) * ldc + col] = f2b(v1);
                    dst[(size_t)(row0 + 2) * ldc + col] = f2b(v2);
                    dst[(size_t)(row0 + 3) * ldc + col] = f2b(v3);
                } else {
                    float* dst = (float*)C0;
                    dst[(size_t)(row0 + 0) * ldc + col] = v0 + bv;
                    dst[(size_t)(row0 + 1) * ldc + col] = v1 + bv;
                    dst[(size_t)(row0 + 2) * ldc + col] = v2 + bv;
                    dst[(size_t)(row0 + 3) * ldc + col] = v3 + bv;
                }
            }
        }
    }
}

// ---------------------------------------------------------------------------
// Row softmax in-place: reads 4096 f16, writes 4096 bf16 over the same bytes.
// ---------------------------------------------------------------------------
__global__ __launch_bounds__(256) void softmax_rows(unsigned short* __restrict__ sc)
{
    const size_t rowoff = (size_t)blockIdx.x * 4096;
    const int t = threadIdx.x;

    h8 a = *(const h8*)(sc + rowoff + t * 8);
    h8 b = *(const h8*)(sc + rowoff + 2048 + t * 8);
    float v[16];
#pragma unroll
    for (int i = 0; i < 8; ++i) { v[i] = (float)a[i]; v[8 + i] = (float)b[i]; }

    float mx = -1e30f;
#pragma unroll
    for (int i = 0; i < 16; ++i) mx = fmaxf(mx, v[i]);
#pragma unroll
    for (int o = 32; o > 0; o >>= 1) mx = fmaxf(mx, __shfl_xor(mx, o));
    __shared__ float redm[4];
    if ((t & 63) == 0) redm[t >> 6] = mx;
    __syncthreads();
    mx = fmaxf(fmaxf(redm[0], redm[1]), fmaxf(redm[2], redm[3]));

    float sum = 0.f;
#pragma unroll
    for (int i = 0; i < 16; ++i) { v[i] = expf(v[i] - mx); sum += v[i]; }
#pragma unroll
    for (int o = 32; o > 0; o >>= 1) sum += __shfl_xor(sum, o);
    __shared__ float reds[4];
    if ((t & 63) == 0) reds[t >> 6] = sum;
    __syncthreads();
    sum = reds[0] + reds[1] + reds[2] + reds[3];
    const float rs = 1.f / sum;

    u16x8 w0, w1;
#pragma unroll
    for (int i = 0; i < 8; ++i) {
        w0[i] = f2b(v[i] * rs);
        w1[i] = f2b(v[8 + i] * rs);
    }
    *(u16x8*)(sc + rowoff + t * 8) = w0;
    *(u16x8*)(sc + rowoff + 2048 + t * 8) = w1;
}

__global__ __launch_bounds__(256) void cast_bf16(
    const float* __restrict__ in, unsigned short* __restrict__ out, int n4)
{
    const int i = blockIdx.x * 256 + threadIdx.x;
    if (i < n4) {
        float4 f = ((const float4*)in)[i];
        ushort4 o;
        o.x = f2b(f.x); o.y = f2b(f.y); o.z = f2b(f.z); o.w = f2b(f.w);
        ((ushort4*)out)[i] = o;
    }
}

// ---------------------------------------------------------------------------
extern "C" void kernel_launch(void* const* d_in, const int* in_sizes, int n_in,
                              void* d_out, int out_size, void* d_ws, size_t ws_size,
                              hipStream_t stream)
{
    const float* x      = (const float*)d_in[0];   // [4,4096,1024]
    const float* qkv_w  = (const float*)d_in[1];   // [3072,1024]
    const float* qkv_b  = (const float*)d_in[2];   // [3072]
    const float* out_w  = (const float*)d_in[3];   // [1024,1024]
    const float* out_b  = (const float*)d_in[4];   // [1024]
    float* out = (float*)d_out;                    // [4,4096,1024] fp32

    unsigned short* W = (unsigned short*)d_ws;
    const size_t M16 = 16777216;   // one [4,4096,1024] bf16 tensor (ushorts)

    if (ws_size >= 236978176ull) {
        // ---- big mode: 226 MiB peak ----
        unsigned short* sc   = W;
        unsigned short* q    = sc + 67108864;
        unsigned short* kk   = q + M16;
        unsigned short* vT   = kk + M16;
        unsigned short* wo   = vT + M16;
        unsigned short* xb   = sc;            // transient, dead before sc write
        unsigned short* wqkv = sc + M16;      // transient
        unsigned short* ao   = q;             // q dead after scores GEMM

        cast_bf16<<<16384, 256, 0, stream>>>(x, xb, 4194304);
        cast_bf16<<<3072, 256, 0, stream>>>(qkv_w, wqkv, 786432);
        cast_bf16<<<1024, 256, 0, stream>>>(out_w, wo, 262144);

        gemm_nt<0, 0><<<12 * 64, 512, 0, stream>>>(
            xb, wqkv, 0, 0, 1024, 1024, 1024, qkv_b, q, kk, vT, 0, 0, 0.f, 12, 64);

        gemm_nt<1, 0><<<16 * 16 * 4, 512, 0, stream>>>(
            q, kk, 4194304, 4194304, 1024, 1024, 1024, nullptr,
            sc, nullptr, nullptr, 16777216, 4096, 0.03125f, 16, 16);

        softmax_rows<<<16384, 256, 0, stream>>>(sc);

        gemm_nt<2, 1><<<4 * 16 * 4, 512, 0, stream>>>(
            sc, vT, 16777216, 4194304, 4096, 4096, 4096, nullptr,
            ao, nullptr, nullptr, 4194304, 1024, 0.f, 4, 16);

        gemm_nt<3, 0><<<4 * 64, 512, 0, stream>>>(
            ao, wo, 0, 0, 1024, 1024, 1024, out_b,
            out, nullptr, nullptr, 0, 1024, 0.f, 4, 64);
    } else {
        // ---- small mode: 168 MiB peak, per-batch scores buffer ----
        unsigned short* sc   = W;
        unsigned short* q    = sc + M16;
        unsigned short* kk   = q + M16;
        unsigned short* vT   = kk + M16;
        unsigned short* ao   = vT + M16;
        unsigned short* wo   = ao + M16;
        unsigned short* wqkv = wo + 1048576;
        unsigned short* xb   = sc;

        cast_bf16<<<16384, 256, 0, stream>>>(x, xb, 4194304);
        cast_bf16<<<3072, 256, 0, stream>>>(qkv_w, wqkv, 786432);
        cast_bf16<<<1024, 256, 0, stream>>>(out_w, wo, 262144);

        gemm_nt<0, 0><<<12 * 64, 512, 0, stream>>>(
            xb, wqkv, 0, 0, 1024, 1024, 1024, qkv_b, q, kk, vT, 0, 0, 0.f, 12, 64);

        for (int z = 0; z < 4; ++z) {
            const size_t zo = (size_t)z * 4194304;
            gemm_nt<1, 0><<<16 * 16, 512, 0, stream>>>(
                q + zo, kk + zo, 0, 0, 1024, 1024, 1024, nullptr,
                sc, nullptr, nullptr, 0, 4096, 0.03125f, 16, 16);
            softmax_rows<<<4096, 256, 0, stream>>>(sc);
            gemm_nt<2, 1><<<4 * 16, 512, 0, stream>>>(
                sc, vT + zo, 0, 0, 4096, 4096, 4096, nullptr,
                ao + zo, nullptr, nullptr, 0, 1024, 0.f, 4, 16);
        }

        gemm_nt<3, 0><<<4 * 64, 512, 0, stream>>>(
            ao, wo, 0, 0, 1024, 1024, 1024, out_b,
            out, nullptr, nullptr, 0, 1024, 0.f, 4, 64);
    }
}

// Round 5
// 473.656 us; speedup vs baseline: 1.0614x; 1.0483x over previous
//
#include <hip/hip_runtime.h>
#include <hip/hip_bf16.h>

typedef __bf16 bf16x8 __attribute__((ext_vector_type(8)));
typedef float f32x4 __attribute__((ext_vector_type(4)));
typedef _Float16 h8 __attribute__((ext_vector_type(8)));
typedef unsigned short u16x8 __attribute__((ext_vector_type(8)));

__device__ inline unsigned short f2b(float x) {
    __hip_bfloat16 h = __float2bfloat16(x);
    return __builtin_bit_cast(unsigned short, h);
}

__device__ inline void gload16(const void* g, void* l) {
    __builtin_amdgcn_global_load_lds(
        (const __attribute__((address_space(1))) unsigned int*)g,
        (__attribute__((address_space(3))) unsigned int*)l, 16, 0, 0);
}

#define BAR  asm volatile("s_barrier" ::: "memory")
#define VMC(N) asm volatile("s_waitcnt vmcnt(" #N ")" ::: "memory")
#define LKM(N) asm volatile("s_waitcnt lgkmcnt(" #N ")")

// reads for one quadrant's A operands (m rows MO, MO+1; both k-halves)
#define RD_A(BASE, MO)                                                \
    af[0][0] = *(const bf16x8*)((BASE) + (MO) * 1024 + aoff0);        \
    af[0][1] = *(const bf16x8*)((BASE) + (MO) * 1024 + aoff1);        \
    af[1][0] = *(const bf16x8*)((BASE) + ((MO) + 1) * 1024 + aoff0);  \
    af[1][1] = *(const bf16x8*)((BASE) + ((MO) + 1) * 1024 + aoff1);

#define RD_B(BASE)                                                    \
    _Pragma("unroll")                                                 \
    for (int n_ = 0; n_ < 4; ++n_) {                                  \
        bfr[n_][0] = *(const bf16x8*)((BASE) + n_ * 1024 + aoff0);    \
        bfr[n_][1] = *(const bf16x8*)((BASE) + n_ * 1024 + aoff1);    \
    }

// 16 MFMA: quadrant m in {MO, MO+1} x 4 n x 2 kk, static acc indices.
#define MFMA_Q(MO)                                                    \
    __builtin_amdgcn_s_setprio(1);                                    \
    _Pragma("unroll")                                                 \
    for (int kk_ = 0; kk_ < 2; ++kk_)                                 \
        _Pragma("unroll")                                             \
        for (int mi_ = 0; mi_ < 2; ++mi_)                             \
            _Pragma("unroll")                                         \
            for (int n_ = 0; n_ < 4; ++n_)                            \
                acc[(MO) + mi_][n_] =                                 \
                    __builtin_amdgcn_mfma_f32_16x16x32_bf16(          \
                        af[mi_][kk_], bfr[n_][kk_],                   \
                        acc[(MO) + mi_][n_], 0, 0, 0);                \
    __builtin_amdgcn_s_setprio(0);

// ---------------------------------------------------------------------------
// NT GEMM: C[M,N] = A[M,K] * B[N,K]^T (+bias), A/B bf16 K-contiguous.
// m198/m201-faithful schedule: 256x256 tile, BK=64, 512 thr = 8 waves (2Mx4N),
// wave tile 128x64, mfma 16x16x32. LDS = 2 bufs x [A0|A1|B0|B1] x 16KiB.
// Iteration = 2 K-tiles (e=2i -> buf0, o=2i+1 -> buf1), 8 phases; per phase:
//   {ds_read quadrant (4; +8 B at p0/p4); stage 1 half-tile (2 gloads);
//    [seals]; barrier; lgkm(0); setprio(1); 16 MFMA; setprio(0); barrier}
// Stage order: p0:A0(o) p1:A1(o) p2:B0(e+2) p3:B1(e+2) p4:A0(e+2) p5:A1(e+2)
//              p6:B0(o+2) p7:B1(o+2)  — each overwrite >=1 barrier after its
// region's reads drained (B(e) read p0, A(e) p0-p3, B(o) p4, A(o) p4-p7).
// Seals (vmcnt is per-wave -> every wait precedes a barrier, dependent reads
// follow that barrier): vmcnt(4) before p3's closing barrier (tile o landed,
// 2 halves fly) and before p7's closing barrier (tile e+2 landed, 2 halves
// fly). Never 0 mid-loop (T4). lgkm(8) partial drain on 12-read phases.
// Prologue stages A0(0),A1(0),B0(0),B1(0),B0(1),B1(1) then vmcnt(4)+barrier —
// identical ledger to steady state. Tail iter: skip stages, vmcnt(0) seal.
// Swizzle (0-conflict, r2-verified): 16B granule g' = g ^ (row&7); source
// pre-swizzled within the row's 128B line, gload_lds dest linear, ds_read
// applies the same involution.
// EPI: 0 = QKV router (bias, q/k normal, v transposed), 1 = f16*scale (scores),
//      2 = bf16 (PV->ao), 3 = f32+bias (final out)
// ---------------------------------------------------------------------------
template<int EPI, int SWZ>
__global__ __launch_bounds__(512, 2) void gemm_nt(
    const unsigned short* __restrict__ A, const unsigned short* __restrict__ B,
    long aZ, long bZ, int lda, int ldb, int K,
    const float* __restrict__ bias,
    void* __restrict__ C0, void* __restrict__ C1, void* __restrict__ C2,
    long cZ, int ldc, float scale, int gx, int gy)
{
    __shared__ __attribute__((aligned(16))) unsigned short lds[2][4][8192];

    int wgid;
    if (SWZ) {
        const int nwg = (int)gridDim.x;
        const int bid = (int)blockIdx.x;
        const int qch = nwg >> 3, rch = nwg & 7;
        const int xcd = bid & 7, idx = bid >> 3;
        wgid = (xcd < rch ? xcd * (qch + 1)
                          : rch * (qch + 1) + (xcd - rch) * qch) + idx;
    } else {
        wgid = (int)blockIdx.x;
    }
    const int bx = wgid % gx;
    const int rem = wgid / gx;
    const int by = rem % gy;
    const int z = rem / gy;

    const int t = threadIdx.x;
    const int lane = t & 63, wid = t >> 6;
    const int wr = wid >> 2, wc = wid & 3;           // 2 x 4 wave grid
    const int tileM = by * 256, tileN = bx * 256;
    A += (size_t)z * aZ;
    B += (size_t)z * bZ;

    f32x4 acc[8][4] = {};

    // ---- read geometry: frag element k = kk*32 + qw*8 (qw = lane>>4);
    // granule g = kk*4+qw; physical g^(row&7), row&7 == lane&7.
    const int l4 = lane & 15, qw = lane >> 4, sw = lane & 7;
    const int aoff0 = l4 * 64 + ((qw ^ sw) << 3);
    const int aoff1 = l4 * 64 + (((4 | qw) ^ sw) << 3);

    // per-wave LDS base pointers (compile-time buffer indices)
    const unsigned short* aB0 = &lds[0][wr][0];
    const unsigned short* aB1 = &lds[1][wr][0];
    const unsigned short* bB0 = &lds[0][2 + (wc >> 1)][0] + (wc & 1) * 4096;
    const unsigned short* bB1 = &lds[1][2 + (wc >> 1)][0] + (wc & 1) * 4096;

    // ---- staging geometry: half-tile = 128 rows x 64 K, 2 gload16/thread.
    // row = t>>3 (+64), phys granule = t&7, src granule = (t ^ (t>>3)) & 7.
    const int srow = t >> 3;
    const int sg = ((t ^ (t >> 3)) & 7) << 3;
    const unsigned short* Asrc = A + (size_t)(tileM + srow) * lda + sg;
    const unsigned short* Bsrc = B + (size_t)(tileN + srow) * ldb + sg;

    auto stageA = [&](int kt, int h) {
        char* dst = (char*)&lds[kt & 1][h][0] + wid * 1024;
        const unsigned short* s = Asrc + (size_t)(h * 128) * lda + kt * 64;
        gload16(s, dst);
        gload16(s + (size_t)64 * lda, dst + 8192);
    };
    auto stageB = [&](int kt, int h) {
        char* dst = (char*)&lds[kt & 1][2 + h][0] + wid * 1024;
        const unsigned short* s = Bsrc + (size_t)(h * 128) * ldb + kt * 64;
        gload16(s, dst);
        gload16(s + (size_t)64 * ldb, dst + 8192);
    };

    const int NT = K >> 6;            // BK=64; K % 128 == 0 here -> NT even
    const int NI = NT >> 1;

    // prologue: tile0 fully + B halves of tile1 (12 loads); seal tile0.
    stageA(0, 0); stageA(0, 1); stageB(0, 0); stageB(0, 1);
    stageB(1, 0); stageB(1, 1);
    VMC(4);
    BAR;

    bf16x8 af[2][2], bfr[4][2];

#pragma unroll 1
    for (int i = 0; i < NI; ++i) {
        const int e = 2 * i, o = e + 1;
        const bool more = (i + 1 < NI);     // stage tiles e+2 / o+2 ?

        // ---- p0: B(e) + A(e,m0-1); stage A0(o)
        RD_B(bB0); RD_A(aB0, 0);
        stageA(o, 0);
        LKM(8);
        BAR; LKM(0); MFMA_Q(0); BAR;

        // ---- p1: A(e,m2-3); stage A1(o)
        RD_A(aB0, 2);
        stageA(o, 1);
        BAR; LKM(0); MFMA_Q(2); BAR;

        // ---- p2: A(e,m4-5); stage B0(e+2)
        RD_A(aB0, 4);
        if (more) stageB(e + 2, 0);
        BAR; LKM(0); MFMA_Q(4); BAR;

        // ---- p3: A(e,m6-7); stage B1(e+2); seal tile o
        RD_A(aB0, 6);
        if (more) stageB(e + 2, 1);
        BAR; LKM(0); MFMA_Q(6);
        if (more) VMC(4); else VMC(0);
        BAR;

        // ---- p4: B(o) + A(o,m0-1); stage A0(e+2)
        RD_B(bB1); RD_A(aB1, 0);
        if (more) stageA(e + 2, 0);
        LKM(8);
        BAR; LKM(0); MFMA_Q(0); BAR;

        // ---- p5: A(o,m2-3); stage A1(e+2)
        RD_A(aB1, 2);
        if (more) stageA(e + 2, 1);
        BAR; LKM(0); MFMA_Q(2); BAR;

        // ---- p6: A(o,m4-5); stage B0(o+2)
        RD_A(aB1, 4);
        if (more) stageB(o + 2, 0);
        BAR; LKM(0); MFMA_Q(4); BAR;

        // ---- p7: A(o,m6-7); stage B1(o+2); seal tile e+2
        RD_A(aB1, 6);
        if (more) stageB(o + 2, 1);
        BAR; LKM(0); MFMA_Q(6);
        if (more) { VMC(4); }
        BAR;
    }

    // epilogue: C/D layout col = lane&15, row = (lane>>4)*4 + j  [m89-verified]
    const int lr = lane >> 4, lc = lane & 15;
#pragma unroll
    for (int m = 0; m < 8; ++m) {
#pragma unroll
        for (int n = 0; n < 4; ++n) {
            f32x4 v = acc[m][n];
            const int col = tileN + wc * 64 + n * 16 + lc;
            const int row0 = tileM + wr * 128 + m * 16 + lr * 4;
            if (EPI == 0) {
                const float bv = bias[col];
                if (col < 2048) {
                    unsigned short* dst = (col < 1024) ? (unsigned short*)C0
                                                       : (unsigned short*)C1;
                    const int cc = col & 1023;
#pragma unroll
                    for (int j = 0; j < 4; ++j)
                        dst[(size_t)(row0 + j) * 1024 + cc] = f2b(v[j] + bv);
                } else {
                    // vT[b][col-2048][s], rows row0..row0+3 are consecutive s
                    const int b = row0 >> 12, s = row0 & 4095;
                    ushort4 h4;
                    h4.x = f2b(v[0] + bv); h4.y = f2b(v[1] + bv);
                    h4.z = f2b(v[2] + bv); h4.w = f2b(v[3] + bv);
                    *(ushort4*)((unsigned short*)C2 +
                                ((size_t)b * 1024 + (col - 2048)) * 4096 + s) = h4;
                }
            } else if (EPI == 1) {
#pragma unroll
                for (int j = 0; j < 4; ++j)
                    ((_Float16*)C0)[(size_t)z * cZ + (size_t)(row0 + j) * ldc + col] =
                        (_Float16)(v[j] * scale);
            } else if (EPI == 2) {
#pragma unroll
                for (int j = 0; j < 4; ++j)
                    ((unsigned short*)C0)[(size_t)z * cZ + (size_t)(row0 + j) * ldc + col] =
                        f2b(v[j]);
            } else {
#pragma unroll
                for (int j = 0; j < 4; ++j)
                    ((float*)C0)[(size_t)(row0 + j) * ldc + col] = v[j] + bias[col];
            }
        }
    }
}

// ---------------------------------------------------------------------------
// Row softmax in-place: reads 4096 f16, writes 4096 bf16 over the same bytes.
// ---------------------------------------------------------------------------
__global__ __launch_bounds__(256) void softmax_rows(unsigned short* __restrict__ sc)
{
    const size_t rowoff = (size_t)blockIdx.x * 4096;
    const int t = threadIdx.x;

    h8 a = *(const h8*)(sc + rowoff + t * 8);
    h8 b = *(const h8*)(sc + rowoff + 2048 + t * 8);
    float v[16];
#pragma unroll
    for (int i = 0; i < 8; ++i) { v[i] = (float)a[i]; v[8 + i] = (float)b[i]; }

    float mx = -1e30f;
#pragma unroll
    for (int i = 0; i < 16; ++i) mx = fmaxf(mx, v[i]);
#pragma unroll
    for (int o = 32; o > 0; o >>= 1) mx = fmaxf(mx, __shfl_xor(mx, o));
    __shared__ float redm[4];
    if ((t & 63) == 0) redm[t >> 6] = mx;
    __syncthreads();
    mx = fmaxf(fmaxf(redm[0], redm[1]), fmaxf(redm[2], redm[3]));

    float sum = 0.f;
#pragma unroll
    for (int i = 0; i < 16; ++i) { v[i] = expf(v[i] - mx); sum += v[i]; }
#pragma unroll
    for (int o = 32; o > 0; o >>= 1) sum += __shfl_xor(sum, o);
    __shared__ float reds[4];
    if ((t & 63) == 0) reds[t >> 6] = sum;
    __syncthreads();
    sum = reds[0] + reds[1] + reds[2] + reds[3];
    const float rs = 1.f / sum;

    u16x8 w0, w1;
#pragma unroll
    for (int i = 0; i < 8; ++i) {
        w0[i] = f2b(v[i] * rs);
        w1[i] = f2b(v[8 + i] * rs);
    }
    *(u16x8*)(sc + rowoff + t * 8) = w0;
    *(u16x8*)(sc + rowoff + 2048 + t * 8) = w1;
}

__global__ __launch_bounds__(256) void cast_bf16(
    const float* __restrict__ in, unsigned short* __restrict__ out, int n4)
{
    const int i = blockIdx.x * 256 + threadIdx.x;
    if (i < n4) {
        float4 f = ((const float4*)in)[i];
        ushort4 o;
        o.x = f2b(f.x); o.y = f2b(f.y); o.z = f2b(f.z); o.w = f2b(f.w);
        ((ushort4*)out)[i] = o;
    }
}

// ---------------------------------------------------------------------------
extern "C" void kernel_launch(void* const* d_in, const int* in_sizes, int n_in,
                              void* d_out, int out_size, void* d_ws, size_t ws_size,
                              hipStream_t stream)
{
    const float* x      = (const float*)d_in[0];   // [4,4096,1024]
    const float* qkv_w  = (const float*)d_in[1];   // [3072,1024]
    const float* qkv_b  = (const float*)d_in[2];   // [3072]
    const float* out_w  = (const float*)d_in[3];   // [1024,1024]
    const float* out_b  = (const float*)d_in[4];   // [1024]
    float* out = (float*)d_out;                    // [4,4096,1024] fp32

    unsigned short* W = (unsigned short*)d_ws;
    const size_t M16 = 16777216;   // one [4,4096,1024] bf16 tensor (ushorts)

    if (ws_size >= 236978176ull) {
        // ---- big mode: 226 MiB peak ----
        unsigned short* sc   = W;
        unsigned short* q    = sc + 67108864;
        unsigned short* kk   = q + M16;
        unsigned short* vT   = kk + M16;
        unsigned short* wo   = vT + M16;
        unsigned short* xb   = sc;            // transient, dead before sc write
        unsigned short* wqkv = sc + M16;      // transient
        unsigned short* ao   = q;             // q dead after scores GEMM

        cast_bf16<<<16384, 256, 0, stream>>>(x, xb, 4194304);
        cast_bf16<<<3072, 256, 0, stream>>>(qkv_w, wqkv, 786432);
        cast_bf16<<<1024, 256, 0, stream>>>(out_w, wo, 262144);

        gemm_nt<0, 0><<<12 * 64, 512, 0, stream>>>(
            xb, wqkv, 0, 0, 1024, 1024, 1024, qkv_b, q, kk, vT, 0, 0, 0.f, 12, 64);

        gemm_nt<1, 0><<<16 * 16 * 4, 512, 0, stream>>>(
            q, kk, 4194304, 4194304, 1024, 1024, 1024, nullptr,
            sc, nullptr, nullptr, 16777216, 4096, 0.03125f, 16, 16);

        softmax_rows<<<16384, 256, 0, stream>>>(sc);

        gemm_nt<2, 1><<<4 * 16 * 4, 512, 0, stream>>>(
            sc, vT, 16777216, 4194304, 4096, 4096, 4096, nullptr,
            ao, nullptr, nullptr, 4194304, 1024, 0.f, 4, 16);

        gemm_nt<3, 0><<<4 * 64, 512, 0, stream>>>(
            ao, wo, 0, 0, 1024, 1024, 1024, out_b,
            out, nullptr, nullptr, 0, 1024, 0.f, 4, 64);
    } else {
        // ---- small mode: 168 MiB peak, per-batch scores buffer ----
        unsigned short* sc   = W;
        unsigned short* q    = sc + M16;
        unsigned short* kk   = q + M16;
        unsigned short* vT   = kk + M16;
        unsigned short* ao   = vT + M16;
        unsigned short* wo   = ao + M16;
        unsigned short* wqkv = wo + 1048576;
        unsigned short* xb   = sc;

        cast_bf16<<<16384, 256, 0, stream>>>(x, xb, 4194304);
        cast_bf16<<<3072, 256, 0, stream>>>(qkv_w, wqkv, 786432);
        cast_bf16<<<1024, 256, 0, stream>>>(out_w, wo, 262144);

        gemm_nt<0, 0><<<12 * 64, 512, 0, stream>>>(
            xb, wqkv, 0, 0, 1024, 1024, 1024, qkv_b, q, kk, vT, 0, 0, 0.f, 12, 64);

        for (int z = 0; z < 4; ++z) {
            const size_t zo = (size_t)z * 4194304;
            gemm_nt<1, 0><<<16 * 16, 512, 0, stream>>>(
                q + zo, kk + zo, 0, 0, 1024, 1024, 1024, nullptr,
                sc, nullptr, nullptr, 0, 4096, 0.03125f, 16, 16);
            softmax_rows<<<4096, 256, 0, stream>>>(sc);
            gemm_nt<2, 1><<<4 * 16, 512, 0, stream>>>(
                sc, vT + zo, 0, 0, 4096, 4096, 4096, nullptr,
                ao + zo, nullptr, nullptr, 0, 1024, 0.f, 4, 16);
        }

        gemm_nt<3, 0><<<4 * 64, 512, 0, stream>>>(
            ao, wo, 0, 0, 1024, 1024, 1024, out_b,
            out, nullptr, nullptr, 0, 1024, 0.f, 4, 64);
    }
}

// Round 6
// 441.937 us; speedup vs baseline: 1.1376x; 1.0718x over previous
//
#include <hip/hip_runtime.h>
#include <hip/hip_bf16.h>

typedef __bf16 bf16x8 __attribute__((ext_vector_type(8)));
typedef float f32x4 __attribute__((ext_vector_type(4)));
typedef _Float16 h8 __attribute__((ext_vector_type(8)));
typedef unsigned short u16x8 __attribute__((ext_vector_type(8)));

__device__ inline unsigned short f2b(float x) {
    __hip_bfloat16 h = __float2bfloat16(x);
    return __builtin_bit_cast(unsigned short, h);
}

__device__ inline void gload16(const void* g, void* l) {
    __builtin_amdgcn_global_load_lds(
        (const __attribute__((address_space(1))) unsigned int*)g,
        (__attribute__((address_space(3))) unsigned int*)l, 16, 0, 0);
}

#define BAR  asm volatile("s_barrier" ::: "memory")
#define VMC(N) asm volatile("s_waitcnt vmcnt(" #N ")" ::: "memory")

// reads for one quadrant's A operands (m rows MO, MO+1; both k-halves)
#define RD_A(BASE, MO)                                                \
    af[0][0] = *(const bf16x8*)((BASE) + (MO) * 1024 + aoff0);        \
    af[0][1] = *(const bf16x8*)((BASE) + (MO) * 1024 + aoff1);        \
    af[1][0] = *(const bf16x8*)((BASE) + ((MO) + 1) * 1024 + aoff0);  \
    af[1][1] = *(const bf16x8*)((BASE) + ((MO) + 1) * 1024 + aoff1);

#define RD_B(BASE)                                                    \
    _Pragma("unroll")                                                 \
    for (int n_ = 0; n_ < 4; ++n_) {                                  \
        bfr[n_][0] = *(const bf16x8*)((BASE) + n_ * 1024 + aoff0);    \
        bfr[n_][1] = *(const bf16x8*)((BASE) + n_ * 1024 + aoff1);    \
    }

// 16 MFMA: quadrant m in {MO, MO+1} x 4 n x 2 kk, static acc indices.
// Compiler inserts the lgkm waits before first af/bfr use (rule-#18-safe).
#define MFMA_Q(MO)                                                    \
    __builtin_amdgcn_s_setprio(1);                                    \
    _Pragma("unroll")                                                 \
    for (int kk_ = 0; kk_ < 2; ++kk_)                                 \
        _Pragma("unroll")                                             \
        for (int mi_ = 0; mi_ < 2; ++mi_)                             \
            _Pragma("unroll")                                         \
            for (int n_ = 0; n_ < 4; ++n_)                            \
                acc[(MO) + mi_][n_] =                                 \
                    __builtin_amdgcn_mfma_f32_16x16x32_bf16(          \
                        af[mi_][kk_], bfr[n_][kk_],                   \
                        acc[(MO) + mi_][n_], 0, 0, 0);                \
    __builtin_amdgcn_s_setprio(0);

// ---------------------------------------------------------------------------
// NT GEMM: C[M,N] = A[M,K] * B[N,K]^T (+bias), A/B bf16 K-contiguous.
// 8-phase / 2-K-tile schedule, ONE barrier per phase, stage issued in the
// MFMA shadow. 256x256 tile, BK=64, 512 thr = 8 waves (2Mx4N), wave tile
// 128x64, mfma 16x16x32. LDS = 2 bufs x [A0|A1|B0|B1] x 16KiB = 128 KiB.
// Phase p: { 4 (or 12) ds_read; [seal vmcnt before BAR at p3/p7]; s_barrier;
//            stage 1 half-tile (2 gload_lds, post-barrier -> overlaps MFMA);
//            setprio(1); 16 MFMA; setprio(0) }
// Safety: a wave arrives at BAR(p+1) only after MFMA(p) issued, which is
// after its phase-p reads drained (compiler lgkm wait) -> all waves past a
// barrier implies all previous-phase reads drained; every LDS overwrite has
// >=1 phase separation from its region's last read. Stages: p0/p1: A(o);
// p2/p3: B(e+2); p4/p5: A(e+2); p6/p7: B(o+2). Seals: VMC(2) before BAR3
// (tile o landed; newest half B0(e+2) flies) and before BAR7 (tile e+2
// landed; B0(o+2) flies) — never 0 mid-loop (T4). Tail iter peeled
// (branch-free steady loop), seals VMC(0) at its p3.
// Swizzle (0-conflict, r2-verified): 16B granule g' = g ^ (row&7); source
// pre-swizzled within the row's 128B line, gload_lds dest linear, ds_read
// applies the same involution.
// EPI: 0 = QKV router (bias, q/k normal, v transposed), 1 = f16*scale (scores),
//      2 = bf16 (PV->ao), 3 = f32+bias (final out)
// ---------------------------------------------------------------------------
template<int EPI, int SWZ>
__global__ __launch_bounds__(512, 2) void gemm_nt(
    const unsigned short* __restrict__ A, const unsigned short* __restrict__ B,
    long aZ, long bZ, int lda, int ldb, int K,
    const float* __restrict__ bias,
    void* __restrict__ C0, void* __restrict__ C1, void* __restrict__ C2,
    long cZ, int ldc, float scale, int gx, int gy)
{
    __shared__ __attribute__((aligned(16))) unsigned short lds[2][4][8192];

    int wgid;
    if (SWZ) {
        const int nwg = (int)gridDim.x;
        const int bid = (int)blockIdx.x;
        const int qch = nwg >> 3, rch = nwg & 7;
        const int xcd = bid & 7, idx = bid >> 3;
        wgid = (xcd < rch ? xcd * (qch + 1)
                          : rch * (qch + 1) + (xcd - rch) * qch) + idx;
    } else {
        wgid = (int)blockIdx.x;
    }
    const int bx = wgid % gx;
    const int rem = wgid / gx;
    const int by = rem % gy;
    const int z = rem / gy;

    const int t = threadIdx.x;
    const int lane = t & 63, wid = t >> 6;
    const int wr = wid >> 2, wc = wid & 3;           // 2 x 4 wave grid
    const int tileM = by * 256, tileN = bx * 256;
    A += (size_t)z * aZ;
    B += (size_t)z * bZ;

    f32x4 acc[8][4] = {};

    // ---- read geometry: frag element k = kk*32 + qw*8 (qw = lane>>4);
    // granule g = kk*4+qw; physical g^(row&7), row&7 == lane&7.
    const int l4 = lane & 15, qw = lane >> 4, sw = lane & 7;
    const int aoff0 = l4 * 64 + ((qw ^ sw) << 3);
    const int aoff1 = l4 * 64 + (((4 | qw) ^ sw) << 3);

    // per-wave LDS read bases (compile-time buffer indices)
    const unsigned short* aB0 = &lds[0][wr][0];
    const unsigned short* aB1 = &lds[1][wr][0];
    const unsigned short* bB0 = &lds[0][2 + (wc >> 1)][0] + (wc & 1) * 4096;
    const unsigned short* bB1 = &lds[1][2 + (wc >> 1)][0] + (wc & 1) * 4096;

    // staging dest bases
    char* const ldsA[2] = {(char*)&lds[0][0][0], (char*)&lds[1][0][0]};
    char* const ldsB[2] = {(char*)&lds[0][2][0], (char*)&lds[1][2][0]};

    // ---- staging geometry: half-tile = 128 rows x 64 K, 2 gload16/thread.
    // row = t>>3 (+64), phys granule = t&7, src granule = (t ^ (t>>3)) & 7.
    const int srow = t >> 3;
    const int sg = ((t ^ (t >> 3)) & 7) << 3;
    const unsigned short* Asrc0 = A + (size_t)(tileM + srow) * lda + sg;
    const unsigned short* Asrc1 = Asrc0 + (size_t)128 * lda;
    const unsigned short* Bsrc0 = B + (size_t)(tileN + srow) * ldb + sg;
    const unsigned short* Bsrc1 = Bsrc0 + (size_t)128 * ldb;

    auto stageA = [&](char* Lb, int koff, int h) {
        char* dst = Lb + h * 16384 + wid * 1024;
        const unsigned short* s = (h ? Asrc1 : Asrc0) + koff;
        gload16(s, dst);
        gload16(s + (size_t)64 * lda, dst + 8192);
    };
    auto stageB = [&](char* Lb, int koff, int h) {
        char* dst = Lb + h * 16384 + wid * 1024;
        const unsigned short* s = (h ? Bsrc1 : Bsrc0) + koff;
        gload16(s, dst);
        gload16(s + (size_t)64 * ldb, dst + 8192);
    };

    const int NT = K >> 6;            // BK=64; K % 128 == 0 here -> NT even
    const int NI = NT >> 1;

    // prologue: tile0 fully + B halves of tile1; seal tile0 (B(1) flies).
    stageA(ldsA[0], 0, 0); stageA(ldsA[0], 0, 1);
    stageB(ldsB[0], 0, 0); stageB(ldsB[0], 0, 1);
    stageB(ldsB[1], 64, 0); stageB(ldsB[1], 64, 1);
    VMC(4);
    BAR;

    bf16x8 af[2][2], bfr[4][2];

#pragma unroll 1
    for (int i = 0; i < NI - 1; ++i) {
        const int kb = i * 128;
        const int ko = kb + 64, ke2 = kb + 128, ko2 = kb + 192;

        // p0
        RD_B(bB0); RD_A(aB0, 0);
        BAR; stageA(ldsA[1], ko, 0);
        MFMA_Q(0)
        // p1
        RD_A(aB0, 2);
        BAR; stageA(ldsA[1], ko, 1);
        MFMA_Q(2)
        // p2
        RD_A(aB0, 4);
        BAR; stageB(ldsB[0], ke2, 0);
        MFMA_Q(4)
        // p3: seal tile o (newest half B0(e+2) may fly)
        RD_A(aB0, 6);
        VMC(2);
        BAR; stageB(ldsB[0], ke2, 1);
        MFMA_Q(6)
        // p4
        RD_B(bB1); RD_A(aB1, 0);
        BAR; stageA(ldsA[0], ke2, 0);
        MFMA_Q(0)
        // p5
        RD_A(aB1, 2);
        BAR; stageA(ldsA[0], ke2, 1);
        MFMA_Q(2)
        // p6
        RD_A(aB1, 4);
        BAR; stageB(ldsB[1], ko2, 0);
        MFMA_Q(4)
        // p7: seal tile e+2 (newest half B0(o+2) may fly)
        RD_A(aB1, 6);
        VMC(2);
        BAR; stageB(ldsB[1], ko2, 1);
        MFMA_Q(6)
    }

    {   // ---- peeled final iteration (no future stages)
        const int ko = (NI - 1) * 128 + 64;
        RD_B(bB0); RD_A(aB0, 0);
        BAR; stageA(ldsA[1], ko, 0);
        MFMA_Q(0)
        RD_A(aB0, 2);
        BAR; stageA(ldsA[1], ko, 1);
        MFMA_Q(2)
        RD_A(aB0, 4);
        BAR;
        MFMA_Q(4)
        RD_A(aB0, 6);
        VMC(0);
        BAR;
        MFMA_Q(6)
        RD_B(bB1); RD_A(aB1, 0);
        BAR;
        MFMA_Q(0)
        RD_A(aB1, 2);
        BAR;
        MFMA_Q(2)
        RD_A(aB1, 4);
        BAR;
        MFMA_Q(4)
        RD_A(aB1, 6);
        BAR;
        MFMA_Q(6)
    }

    // epilogue: C/D layout col = lane&15, row = (lane>>4)*4 + j  [m89-verified]
    const int lr = lane >> 4, lc = lane & 15;
#pragma unroll
    for (int m = 0; m < 8; ++m) {
#pragma unroll
        for (int n = 0; n < 4; ++n) {
            f32x4 v = acc[m][n];
            const int col = tileN + wc * 64 + n * 16 + lc;
            const int row0 = tileM + wr * 128 + m * 16 + lr * 4;
            if (EPI == 0) {
                const float bv = bias[col];
                if (col < 2048) {
                    unsigned short* dst = (col < 1024) ? (unsigned short*)C0
                                                       : (unsigned short*)C1;
                    const int cc = col & 1023;
#pragma unroll
                    for (int j = 0; j < 4; ++j)
                        dst[(size_t)(row0 + j) * 1024 + cc] = f2b(v[j] + bv);
                } else {
                    // vT[b][col-2048][s], rows row0..row0+3 are consecutive s
                    const int b = row0 >> 12, s = row0 & 4095;
                    ushort4 h4;
                    h4.x = f2b(v[0] + bv); h4.y = f2b(v[1] + bv);
                    h4.z = f2b(v[2] + bv); h4.w = f2b(v[3] + bv);
                    *(ushort4*)((unsigned short*)C2 +
                                ((size_t)b * 1024 + (col - 2048)) * 4096 + s) = h4;
                }
            } else if (EPI == 1) {
#pragma unroll
                for (int j = 0; j < 4; ++j)
                    ((_Float16*)C0)[(size_t)z * cZ + (size_t)(row0 + j) * ldc + col] =
                        (_Float16)(v[j] * scale);
            } else if (EPI == 2) {
#pragma unroll
                for (int j = 0; j < 4; ++j)
                    ((unsigned short*)C0)[(size_t)z * cZ + (size_t)(row0 + j) * ldc + col] =
                        f2b(v[j]);
            } else {
#pragma unroll
                for (int j = 0; j < 4; ++j)
                    ((float*)C0)[(size_t)(row0 + j) * ldc + col] = v[j] + bias[col];
            }
        }
    }
}

// ---------------------------------------------------------------------------
// Row softmax in-place: reads 4096 f16, writes 4096 bf16 over the same bytes.
// ---------------------------------------------------------------------------
__global__ __launch_bounds__(256) void softmax_rows(unsigned short* __restrict__ sc)
{
    const size_t rowoff = (size_t)blockIdx.x * 4096;
    const int t = threadIdx.x;

    h8 a = *(const h8*)(sc + rowoff + t * 8);
    h8 b = *(const h8*)(sc + rowoff + 2048 + t * 8);
    float v[16];
#pragma unroll
    for (int i = 0; i < 8; ++i) { v[i] = (float)a[i]; v[8 + i] = (float)b[i]; }

    float mx = -1e30f;
#pragma unroll
    for (int i = 0; i < 16; ++i) mx = fmaxf(mx, v[i]);
#pragma unroll
    for (int o = 32; o > 0; o >>= 1) mx = fmaxf(mx, __shfl_xor(mx, o));
    __shared__ float redm[4];
    if ((t & 63) == 0) redm[t >> 6] = mx;
    __syncthreads();
    mx = fmaxf(fmaxf(redm[0], redm[1]), fmaxf(redm[2], redm[3]));

    float sum = 0.f;
#pragma unroll
    for (int i = 0; i < 16; ++i) { v[i] = expf(v[i] - mx); sum += v[i]; }
#pragma unroll
    for (int o = 32; o > 0; o >>= 1) sum += __shfl_xor(sum, o);
    __shared__ float reds[4];
    if ((t & 63) == 0) reds[t >> 6] = sum;
    __syncthreads();
    sum = reds[0] + reds[1] + reds[2] + reds[3];
    const float rs = 1.f / sum;

    u16x8 w0, w1;
#pragma unroll
    for (int i = 0; i < 8; ++i) {
        w0[i] = f2b(v[i] * rs);
        w1[i] = f2b(v[8 + i] * rs);
    }
    *(u16x8*)(sc + rowoff + t * 8) = w0;
    *(u16x8*)(sc + rowoff + 2048 + t * 8) = w1;
}

__global__ __launch_bounds__(256) void cast_bf16(
    const float* __restrict__ in, unsigned short* __restrict__ out, int n4)
{
    const int i = blockIdx.x * 256 + threadIdx.x;
    if (i < n4) {
        float4 f = ((const float4*)in)[i];
        ushort4 o;
        o.x = f2b(f.x); o.y = f2b(f.y); o.z = f2b(f.z); o.w = f2b(f.w);
        ((ushort4*)out)[i] = o;
    }
}

// ---------------------------------------------------------------------------
extern "C" void kernel_launch(void* const* d_in, const int* in_sizes, int n_in,
                              void* d_out, int out_size, void* d_ws, size_t ws_size,
                              hipStream_t stream)
{
    const float* x      = (const float*)d_in[0];   // [4,4096,1024]
    const float* qkv_w  = (const float*)d_in[1];   // [3072,1024]
    const float* qkv_b  = (const float*)d_in[2];   // [3072]
    const float* out_w  = (const float*)d_in[3];   // [1024,1024]
    const float* out_b  = (const float*)d_in[4];   // [1024]
    float* out = (float*)d_out;                    // [4,4096,1024] fp32

    unsigned short* W = (unsigned short*)d_ws;
    const size_t M16 = 16777216;   // one [4,4096,1024] bf16 tensor (ushorts)

    if (ws_size >= 236978176ull) {
        // ---- big mode: 226 MiB peak ----
        unsigned short* sc   = W;
        unsigned short* q    = sc + 67108864;
        unsigned short* kk   = q + M16;
        unsigned short* vT   = kk + M16;
        unsigned short* wo   = vT + M16;
        unsigned short* xb   = sc;            // transient, dead before sc write
        unsigned short* wqkv = sc + M16;      // transient
        unsigned short* ao   = q;             // q dead after scores GEMM

        cast_bf16<<<16384, 256, 0, stream>>>(x, xb, 4194304);
        cast_bf16<<<3072, 256, 0, stream>>>(qkv_w, wqkv, 786432);
        cast_bf16<<<1024, 256, 0, stream>>>(out_w, wo, 262144);

        gemm_nt<0, 0><<<12 * 64, 512, 0, stream>>>(
            xb, wqkv, 0, 0, 1024, 1024, 1024, qkv_b, q, kk, vT, 0, 0, 0.f, 12, 64);

        gemm_nt<1, 0><<<16 * 16 * 4, 512, 0, stream>>>(
            q, kk, 4194304, 4194304, 1024, 1024, 1024, nullptr,
            sc, nullptr, nullptr, 16777216, 4096, 0.03125f, 16, 16);

        softmax_rows<<<16384, 256, 0, stream>>>(sc);

        gemm_nt<2, 1><<<4 * 16 * 4, 512, 0, stream>>>(
            sc, vT, 16777216, 4194304, 4096, 4096, 4096, nullptr,
            ao, nullptr, nullptr, 4194304, 1024, 0.f, 4, 16);

        gemm_nt<3, 0><<<4 * 64, 512, 0, stream>>>(
            ao, wo, 0, 0, 1024, 1024, 1024, out_b,
            out, nullptr, nullptr, 0, 1024, 0.f, 4, 64);
    } else {
        // ---- small mode: 168 MiB peak, per-batch scores buffer ----
        unsigned short* sc   = W;
        unsigned short* q    = sc + M16;
        unsigned short* kk   = q + M16;
        unsigned short* vT   = kk + M16;
        unsigned short* ao   = vT + M16;
        unsigned short* wo   = ao + M16;
        unsigned short* wqkv = wo + 1048576;
        unsigned short* xb   = sc;

        cast_bf16<<<16384, 256, 0, stream>>>(x, xb, 4194304);
        cast_bf16<<<3072, 256, 0, stream>>>(qkv_w, wqkv, 786432);
        cast_bf16<<<1024, 256, 0, stream>>>(out_w, wo, 262144);

        gemm_nt<0, 0><<<12 * 64, 512, 0, stream>>>(
            xb, wqkv, 0, 0, 1024, 1024, 1024, qkv_b, q, kk, vT, 0, 0, 0.f, 12, 64);

        for (int z = 0; z < 4; ++z) {
            const size_t zo = (size_t)z * 4194304;
            gemm_nt<1, 0><<<16 * 16, 512, 0, stream>>>(
                q + zo, kk + zo, 0, 0, 1024, 1024, 1024, nullptr,
                sc, nullptr, nullptr, 0, 4096, 0.03125f, 16, 16);
            softmax_rows<<<4096, 256, 0, stream>>>(sc);
            gemm_nt<2, 1><<<4 * 16, 512, 0, stream>>>(
                sc, vT + zo, 0, 0, 4096, 4096, 4096, nullptr,
                ao + zo, nullptr, nullptr, 0, 1024, 0.f, 4, 16);
        }

        gemm_nt<3, 0><<<4 * 64, 512, 0, stream>>>(
            ao, wo, 0, 0, 1024, 1024, 1024, out_b,
            out, nullptr, nullptr, 0, 1024, 0.f, 4, 64);
    }
}